// Round 9
// baseline (235.495 us; speedup 1.0000x reference)
//
#include <hip/hip_runtime.h>
#include <math.h>

#define TT    32
#define NN    100000
#define FF    2
#define ROW   64        // TT*FF floats per node row
#define EE    1600000
#define MAXIT 20
#define LDSROW 66       // 64 + 2 pad: <=2-way LDS aliasing (free on CDNA4)
#define BIGIT (1 << 29) // fill_iter value for "no data yet" == all-zero row
#define NR    8         // XCD dst-range bins
#define RNG   (NN / NR) // 12500 nodes per bin
#define SLOT  28        // fixed valid slots per node (Poisson(8) in-deg; P(>28)~1e-20)
#define QCAP   131072   // per-bin valid-edge queue capacity (expected ~100K, ~100 sigma)
#define IQCAP  442368   // invalid-edge queue capacity (expected ~400K, ~67 sigma)
#define CIDCAP 2048     // compact ids for nodes with cnt_v==0 (expected ~17)
#define CHUNK  782      // edges per k_compact block (2047 blocks cover EE)
#define NWORD  3126     // ceil(100032/32) bit-array words (12.5 KB -> L1-resident)
#define GFB    1792     // gather blocks in fused gf_inv kernel (+256 inv blocks)

typedef float f32x4 __attribute__((ext_vector_type(4)));
typedef float f32x2 __attribute__((ext_vector_type(2)));

__device__ __forceinline__ float fsig(float x) { return 1.0f / (1.0f + __expf(-x)); }
__device__ __forceinline__ float ftanh(float x) { return 2.0f / (1.0f + __expf(-2.0f * x)) - 1.0f; }

__device__ __forceinline__ bool bit_test(const unsigned int* __restrict__ b, int n) {
    return (b[n >> 5] >> (n & 31)) & 1u;
}

// ---------------------------------------------------------------------------
// Fused: mask + transpose [T,N,F]->[N][64] + fill_iter + hz/hd BIT arrays +
// dirty-bitmap zero + zero-init of cnt_v/cidmap/icnt/qc/wl_count.
// hz/hd are 12.5KB bit arrays (L1-resident; k_compact/gather probe them 1.6M+
// times). Each block owns exactly 2 bit-words, plain stores, no atomics.
// Staging is the PROVEN round-1 pattern: scalar 4B NT loads + scalar tile
// stores (2-way bank aliasing = free). Round-4's vectorized version ran 3x
// slower (LDS conflicts + branchy bounds) -- do not re-vectorize this staging.
__global__ void k_mt_flags(const float* __restrict__ x, const int* __restrict__ mask,
                           float* __restrict__ xx, int* __restrict__ fill_iter,
                           unsigned int* __restrict__ hzb, unsigned int* __restrict__ hdb,
                           unsigned int* __restrict__ dzb,
                           int* __restrict__ cnt_v, int* __restrict__ cidmap,
                           int* __restrict__ icnt, int* __restrict__ qc,
                           int* __restrict__ wl_count) {
    __shared__ float tile[64 * LDSROW];
    __shared__ unsigned int wmH[4], wmD[4];
    const int n0 = blockIdx.x * 64;
    const int tid = threadIdx.x;

    // fused init
    if (tid < 64 && n0 + tid < NN) { cnt_v[n0 + tid] = 0; cidmap[n0 + tid] = 0; }
    if (blockIdx.x == 0) {
        if (tid < 32) wl_count[tid] = 0;
        if (tid >= 32 && tid < 48) qc[tid - 32] = 0;
    }
    if (blockIdx.x < 8) icnt[blockIdx.x * 256 + tid] = 0;
    if (tid < 2) dzb[2 * blockIdx.x + tid] = 0u;     // dirty bitmap zero

#pragma unroll
    for (int r = 0; r < 16; r++) {
        int flat = r * 256 + tid;          // 0..4095
        int t = flat >> 7;
        int col = flat & 127;
        int gcol = n0 * 2 + col;
        if (gcol < NN * FF) {
            int n = n0 + (col >> 1);
            float v = __builtin_nontemporal_load(x + (size_t)t * (NN * FF) + gcol);
            v = mask[n] ? v : 0.0f;
            tile[(col >> 1) * LDSROW + t * 2 + (col & 1)] = v;
        }
    }
    __syncthreads();

    const int lane = tid & 63, w = tid >> 6;
    unsigned int mwave = 0, dwave = 0;       // hz / hd bits for this wave's 16 nodes
    for (int i = 0; i < 16; i++) {
        int ln = w * 16 + i;
        int n = n0 + ln;
        if (n >= NN) break;                          // wave-uniform
        float v = tile[ln * LDSROW + lane];
        unsigned long long nzm = __ballot(v != 0.0f);
        if (nzm != ~0ull) mwave |= (1u << i);        // row has at least one zero
        if (nzm != 0ull)  dwave |= (1u << i);        // row has at least one datum
        if (lane == 0) fill_iter[n] = (nzm != 0ull) ? 0 : BIGIT;
    }
    if (lane == 0) { wmH[w] = mwave; wmD[w] = dwave; }
    __syncthreads();
    if (tid == 0) {
        hzb[2 * blockIdx.x]     = wmH[0] | (wmH[1] << 16);
        hzb[2 * blockIdx.x + 1] = wmH[2] | (wmH[3] << 16);
        hdb[2 * blockIdx.x]     = wmD[0] | (wmD[1] << 16);
        hdb[2 * blockIdx.x + 1] = wmD[2] | (wmD[3] << 16);
    }

#pragma unroll
    for (int j = 0; j < 4; j++) {
        int flat4 = j * 256 + tid;
        int ln = flat4 >> 4;
        int n = n0 + ln;
        if (n >= NN) continue;
        int off = (flat4 & 15) * 4;
        float4 v;
        v.x = tile[ln * LDSROW + off + 0];
        v.y = tile[ln * LDSROW + off + 1];
        v.z = tile[ln * LDSROW + off + 2];
        v.w = tile[ln * LDSROW + off + 3];
        *(float4*)(xx + (size_t)n * ROW + off) = v;
    }
}

// ---------------------------------------------------------------------------
// Pass A: ONE coalesced NT scan of the edge list. Kept edges (hz dst) binned
// block-locally in LDS into 8 dst-range valid queues + 1 global invalid
// queue; one global atomic per queue per block. src load is UNCONDITIONAL:
// breaks the dst-load -> bit-test -> src-load dependent chain.
__global__ void k_compact(const int* __restrict__ ei, const unsigned int* __restrict__ hzb,
                          const unsigned int* __restrict__ hdb,
                          int2* __restrict__ vq, int2* __restrict__ iq,
                          int* __restrict__ qc) {
    __shared__ int lcnt[9];
    __shared__ int lbase[9];
    const int tid = threadIdx.x;
    if (tid < 9) lcnt[tid] = 0;
    __syncthreads();
    const int e0 = blockIdx.x * CHUNK;
    const int e1 = min(e0 + CHUNK, EE);
    int rs[4], rd[4], rb[4], rp[4];
#pragma unroll
    for (int i = 0; i < 4; i++) {
        rb[i] = -1;
        int e = e0 + i * 256 + tid;
        if (e < e1) {
            int dst = __builtin_nontemporal_load(ei + EE + e);
            int src = __builtin_nontemporal_load(ei + e);   // unconditional
            if (bit_test(hzb, dst)) {
                int b = bit_test(hdb, src) ? (dst / RNG) : 8;
                rs[i] = src; rd[i] = dst; rb[i] = b;
                rp[i] = atomicAdd(&lcnt[b], 1);
            }
        }
    }
    __syncthreads();
    if (tid < 9) lbase[tid] = atomicAdd(&qc[tid], lcnt[tid]);
    __syncthreads();
#pragma unroll
    for (int i = 0; i < 4; i++) {
        if (rb[i] >= 0) {
            int b = rb[i];
            int p = lbase[b] + rp[i];
            if (b < 8) { if (p < QCAP)  vq[b * QCAP + p] = make_int2(rs[i], rd[i]); }
            else       { if (p < IQCAP) iq[p]            = make_int2(rs[i], rd[i]); }
        }
    }
}

// ---------------------------------------------------------------------------
// Pass B: per-XCD bin drains its own queue into its slab slice. Queue (~800KB)
// and slab slice (1.4MB) both stay resident in the bin's L2.
__global__ void k_build(const int2* __restrict__ vq, const int* __restrict__ qc,
                        int* __restrict__ cnt_v, int* __restrict__ slab) {
    const int r = blockIdx.x & 7;
    int n = qc[r]; if (n > QCAP) n = QCAP;
    const int gid = (blockIdx.x >> 3) * blockDim.x + threadIdx.x;
    const int stride = (gridDim.x >> 3) * blockDim.x;
    const int2* q = vq + r * QCAP;
    for (int i = gid; i < n; i += stride) {
        int2 sd = q[i];
        int pos = atomicAdd(&cnt_v[sd.y], 1);
        if (pos < SLOT) slab[sd.y * SLOT + pos] = sd.x;
    }
}

// ---------------------------------------------------------------------------
// Gather body, 4-way neighbor-parallel. Valid extent needs NO per-edge check;
// invalid extent (tiny slab) checks fill_iter<k. zrow=true skips the 256B
// own-row read. dzb!=null (iter 1): mark appended nodes in the dirty bitmap.
__device__ __forceinline__ void gather_node4(int n, int k, int lane, bool zrow,
                                             int vbeg, int vend, const int* __restrict__ vsl,
                                             int ibeg, int iend, const int* __restrict__ isl,
                                             int* __restrict__ fill_iter,
                                             float* __restrict__ xx,
                                             int* __restrict__ wl_next,
                                             int* __restrict__ wl_count,
                                             unsigned int* __restrict__ dzb) {
    const int g = lane >> 4;
    const int s = lane & 15;
    float ax = 0.f, ay = 0.f, az = 0.f, aw = 0.f, cntv = 0.f;
#pragma unroll 2
    for (int e = vbeg + g; e < vend; e += 4) {
        int src = vsl[e];                      // broadcast within group
        f32x4 v = ((const f32x4*)(xx + (size_t)src * ROW))[s];
        ax += v.x; ay += v.y; az += v.z; aw += v.w; cntv += 1.f;
    }
    for (int e = ibeg + g; e < iend; e += 4) {
        int src = isl[e];
        if (fill_iter[src] < k) {
            f32x4 v = ((const f32x4*)(xx + (size_t)src * ROW))[s];
            ax += v.x; ay += v.y; az += v.z; aw += v.w; cntv += 1.f;
        }
    }
    // reduce the 4 groups (lane xor 16, 32)
#pragma unroll
    for (int d = 16; d <= 32; d <<= 1) {
        ax += __shfl_xor(ax, d, 64);
        ay += __shfl_xor(ay, d, 64);
        az += __shfl_xor(az, d, 64);
        aw += __shfl_xor(aw, d, 64);
        cntv += __shfl_xor(cntv, d, 64);
    }
    f32x4 own;
    if (zrow) { own.x = 0.f; own.y = 0.f; own.z = 0.f; own.w = 0.f; }
    else        own = ((const f32x4*)(xx + (size_t)n * ROW))[s];
    bool has = cntv > 0.f;
    f32x4 nv;
    nv.x = (own.x == 0.f && has) ? ax / cntv : own.x;
    nv.y = (own.y == 0.f && has) ? ay / cntv : own.y;
    nv.z = (own.z == 0.f && has) ? az / cntv : own.z;
    nv.w = (own.w == 0.f && has) ? aw / cntv : own.w;
    bool allnz = (nv.x != 0.f) & (nv.y != 0.f) & (nv.z != 0.f) & (nv.w != 0.f);
    bool anynz = (nv.x != 0.f) | (nv.y != 0.f) | (nv.z != 0.f) | (nv.w != 0.f);
    unsigned long long ba = __ballot(allnz);
    unsigned long long bn = __ballot(anynz);
    if (g == 0) ((f32x4*)(xx + (size_t)n * ROW))[s] = nv;
    if (lane == 0) {
        if (bn != 0ull && fill_iter[n] > k) fill_iter[n] = k;   // now a valid source
        if (ba != ~0ull) {                     // still has zeros -> next worklist
            int pos = atomicAdd(&wl_count[k], 1);
            wl_next[pos] = n;
            if (dzb) atomicOr(&dzb[n >> 5], 1u << (n & 31));
        }
    }
}

// ---------------------------------------------------------------------------
// FUSED iteration-1 gather + invalid-queue build (independent work, one
// dispatch): blocks 0..GFB-1 gather over all nodes (L1 hz bit test); blocks
// GFB..GFB+255 filter the invalid queue (final cnt_v==0 dsts ~17 nodes),
// assign compact ids via CAS, fill the tiny inverse slab.
__global__ void k_gf_inv(const unsigned int* __restrict__ hzb,
                         const unsigned int* __restrict__ hdb,
                         const int* __restrict__ cnt_v, const int* __restrict__ slab,
                         int* __restrict__ fill_iter, float* __restrict__ xx,
                         int* __restrict__ wl_next, int* __restrict__ wl_count,
                         unsigned int* __restrict__ dzb,
                         const int2* __restrict__ iq, const int* __restrict__ qc,
                         int* __restrict__ cidmap, int* __restrict__ icnt,
                         int* __restrict__ islab, int* __restrict__ ncid) {
    if (blockIdx.x >= GFB) {
        // ---- inv part (256 blocks) ----
        int n = qc[8]; if (n > IQCAP) n = IQCAP;
        const int gid = (blockIdx.x - GFB) * blockDim.x + threadIdx.x;
        const int stride = 256 * blockDim.x;
        for (int i = gid; i < n; i += stride) {
            int2 sd = iq[i];
            if (cnt_v[sd.y] != 0) continue;
            int cid = cidmap[sd.y];
            if (cid == 0) {
                int nid = atomicAdd(ncid, 1) + 1;
                int old = atomicCAS(&cidmap[sd.y], 0, nid);
                cid = old ? old : nid;
            }
            if (cid <= CIDCAP) {
                int pos = atomicAdd(&icnt[cid - 1], 1);
                if (pos < SLOT) islab[(cid - 1) * SLOT + pos] = sd.x;
            }
        }
        return;
    }
    // ---- gather part (GFB blocks) ----
    const int lane = threadIdx.x & 63;
    int wave = (blockIdx.x * blockDim.x + threadIdx.x) >> 6;
    const int nwaves = (GFB * blockDim.x) >> 6;
    for (int n0 = wave; n0 < NN; n0 += nwaves) {
        int n = __builtin_amdgcn_readfirstlane(n0);
        unsigned int hzw = __builtin_amdgcn_readfirstlane(hzb[n >> 5]);
        if (!((hzw >> (n & 31)) & 1u)) continue;     // wave-uniform L1 bit test
        int cv = cnt_v[n]; if (cv > SLOT) cv = SLOT;
        unsigned int hdw = __builtin_amdgcn_readfirstlane(hdb[n >> 5]);
        bool zrow = !((hdw >> (n & 31)) & 1u);
        gather_node4(n, 1, lane, zrow, n * SLOT, n * SLOT + cv, slab, 0, 0, slab,
                     fill_iter, xx, wl_next, wl_count, dzb);
    }
}

// ---------------------------------------------------------------------------
// LSTM for one node: hidden=2, gates i,f,g,o. NT loads + NT stores. t-loop
// FULLY unrolled so the 64-float row lives in VGPRs (rule #20).
__device__ __forceinline__ void lstm_node(int n, const float* __restrict__ xx,
                                          const float* __restrict__ wih,
                                          const float* __restrict__ whh,
                                          const float* __restrict__ bih,
                                          const float* __restrict__ bhh,
                                          float* __restrict__ out) {
    float Wi[8][2], Wh[8][2], B[8];
#pragma unroll
    for (int kk = 0; kk < 8; kk++) {
        Wi[kk][0] = wih[kk * 2]; Wi[kk][1] = wih[kk * 2 + 1];
        Wh[kk][0] = whh[kk * 2]; Wh[kk][1] = whh[kk * 2 + 1];
        B[kk] = bih[kk] + bhh[kk];
    }
    f32x4 r4[16];
    const f32x4* row4 = (const f32x4*)(xx + (size_t)n * ROW);
#pragma unroll
    for (int i = 0; i < 16; i++) r4[i] = __builtin_nontemporal_load(row4 + i);

    float h0 = 0.f, h1 = 0.f, c0 = 0.f, c1 = 0.f;
#pragma unroll
    for (int t = 0; t < TT; t++) {
        f32x4 q = r4[t >> 1];                 // compile-time index (full unroll)
        float x0 = (t & 1) ? q.z : q.x;
        float x1 = (t & 1) ? q.w : q.y;
        float g[8];
#pragma unroll
        for (int kk = 0; kk < 8; kk++)
            g[kk] = B[kk] + Wi[kk][0] * x0 + Wi[kk][1] * x1 + Wh[kk][0] * h0 + Wh[kk][1] * h1;
        float i0 = fsig(g[0]), i1 = fsig(g[1]);
        float f0 = fsig(g[2]), f1 = fsig(g[3]);
        float gg0 = ftanh(g[4]), gg1 = ftanh(g[5]);
        float o0 = fsig(g[6]), o1 = fsig(g[7]);
        c0 = f0 * c0 + i0 * gg0;
        c1 = f1 * c1 + i1 * gg1;
        h0 = o0 * ftanh(c0);
        h1 = o1 * ftanh(c1);
        f32x2 hv; hv.x = h0; hv.y = h1;
        __builtin_nontemporal_store(hv, (f32x2*)(out + (size_t)t * (NN * FF) + n * 2));
    }
}

// ---------------------------------------------------------------------------
// FUSED iterations 2..MAXIT + LSTM. SAFE ONLY when all scratch lives in d_ws:
// round-8's version kept scratch in d_out and the clean-node LSTM blocks
// clobbered slab/worklists while block 0 was still gathering -> garbage src
// index -> OOB xx read -> GPU fault (the round-8 core dump). Now d_out is
// pure output. Block 0: persistent gather then LSTM of dirty nodes; blocks
// 1..: LSTM of clean nodes immediately. wl_a (k=1 dirty list) is PRESERVED:
// k=2 reads a->writes b; k>=3 ping-pongs b<->c.
__global__ void k_rest_lstm(int* __restrict__ wl_a, int* __restrict__ wl_b,
                            int* __restrict__ wl_c,
                            int* __restrict__ wl_count,
                            const int* __restrict__ cnt_v, const int* __restrict__ cidmap,
                            const int* __restrict__ icnt, const int* __restrict__ islab,
                            const int* __restrict__ slab,
                            int* __restrict__ fill_iter, float* __restrict__ xx,
                            const unsigned int* __restrict__ dzb,
                            const float* __restrict__ wih, const float* __restrict__ whh,
                            const float* __restrict__ bih, const float* __restrict__ bhh,
                            float* __restrict__ out) {
    if (blockIdx.x == 0) {
        // ---- persistent gather, 4 waves ----
        const int lane = threadIdx.x & 63;
        const int wave = threadIdx.x >> 6;       // 0..3
        for (int k = 2; k <= MAXIT; k++) {
            int cnt = atomicAdd(&wl_count[k - 1], 0);   // L2 read, never stale-L1
            if (cnt == 0) break;                        // uniform across block
            int* prev = (k == 2) ? wl_a : ((k & 1) ? wl_b : wl_c);
            int* next = (k & 1) ? wl_c : wl_b;          // k=2->b, k=3->c, k=4->b...
            for (int w = wave; w < cnt; w += 4) {
                int n = __builtin_amdgcn_readfirstlane(prev[w]);
                int cv = cnt_v[n]; if (cv > SLOT) cv = SLOT;
                int cid = cidmap[n];
                int ci = 0, ib = 0;
                if (cid > 0 && cid <= CIDCAP) {
                    ci = icnt[cid - 1]; if (ci > SLOT) ci = SLOT;
                    ib = (cid - 1) * SLOT;
                }
                bool zrow = (__builtin_amdgcn_readfirstlane(fill_iter[n]) == BIGIT);
                gather_node4(n, k, lane, zrow, n * SLOT, n * SLOT + cv, slab,
                             ib, ib + ci, islab,
                             fill_iter, xx, next, wl_count, (unsigned int*)0);
            }
            __threadfence();
            __syncthreads();
        }
        __threadfence();
        __syncthreads();
        // ---- LSTM for the dirty nodes this block just finished ----
        int cnt1 = wl_count[1]; if (cnt1 > NN) cnt1 = NN;
        for (int i = threadIdx.x; i < cnt1; i += blockDim.x)
            lstm_node(wl_a[i], xx, wih, whh, bih, bhh, out);
        return;
    }
    // ---- LSTM for clean nodes (blocks 1.., one thread per node) ----
    int n = (blockIdx.x - 1) * 256 + threadIdx.x;
    if (n >= NN) return;
    if (bit_test(dzb, n)) return;                // block 0 owns this row
    lstm_node(n, xx, wih, whh, bih, bhh, out);
}

// ---------------------------------------------------------------------------
// Fallback pair for small-ws mode (scratch in d_out): proven round-6 ordering,
// gather_rest completes BEFORE the LSTM dispatch touches d_out.
__global__ __launch_bounds__(1024)
void k_gather_rest(int* __restrict__ wl_a, int* __restrict__ wl_b,
                   int* __restrict__ wl_c, int* __restrict__ wl_count,
                   const int* __restrict__ cnt_v, const int* __restrict__ cidmap,
                   const int* __restrict__ icnt, const int* __restrict__ islab,
                   const int* __restrict__ slab,
                   int* __restrict__ fill_iter, float* __restrict__ xx) {
    const int lane = threadIdx.x & 63;
    const int wave = threadIdx.x >> 6;       // 0..15
    for (int k = 2; k <= MAXIT; k++) {
        int cnt = atomicAdd(&wl_count[k - 1], 0);
        if (cnt == 0) break;
        int* prev = (k == 2) ? wl_a : ((k & 1) ? wl_b : wl_c);
        int* next = (k & 1) ? wl_c : wl_b;
        for (int w = wave; w < cnt; w += 16) {
            int n = __builtin_amdgcn_readfirstlane(prev[w]);
            int cv = cnt_v[n]; if (cv > SLOT) cv = SLOT;
            int cid = cidmap[n];
            int ci = 0, ib = 0;
            if (cid > 0 && cid <= CIDCAP) {
                ci = icnt[cid - 1]; if (ci > SLOT) ci = SLOT;
                ib = (cid - 1) * SLOT;
            }
            bool zrow = (__builtin_amdgcn_readfirstlane(fill_iter[n]) == BIGIT);
            gather_node4(n, k, lane, zrow, n * SLOT, n * SLOT + cv, slab,
                         ib, ib + ci, islab,
                         fill_iter, xx, next, wl_count, (unsigned int*)0);
        }
        __threadfence();
        __syncthreads();
    }
}

__global__ void k_lstm_all(const float* __restrict__ xx,
                           const float* __restrict__ wih, const float* __restrict__ whh,
                           const float* __restrict__ bih, const float* __restrict__ bhh,
                           float* __restrict__ out) {
    int n = blockIdx.x * 64 + threadIdx.x;
    if (n >= NN) return;
    lstm_node(n, xx, wih, whh, bih, bhh, out);
}

// ---------------------------------------------------------------------------
extern "C" void kernel_launch(void* const* d_in, const int* in_sizes, int n_in,
                              void* d_out, int out_size, void* d_ws, size_t ws_size,
                              hipStream_t stream) {
    const float* x    = (const float*)d_in[0];   // [T,N,F]
    const int*   ei   = (const int*)d_in[1];     // [2,E]
    const int*   mask = (const int*)d_in[2];     // [N]
    const float* wih  = (const float*)d_in[6];
    const float* whh  = (const float*)d_in[7];
    const float* bih  = (const float*)d_in[8];
    const float* bhh  = (const float*)d_in[9];
    float* out = (float*)d_out;                  // [T,N,F] fp32

    // Fixed ws region: xx (25.6 MB) + fill_iter + wl_count + hzb/hdb/dzb
    char* ws = (char*)d_ws;
    float* xx        = (float*)ws;
    int*   fill_iter = (int*)(ws + (size_t)NN * ROW * 4);
    int*   wl_count  = fill_iter + NN;
    unsigned int* hzb = (unsigned int*)(wl_count + 32);
    unsigned int* hdb = hzb + NWORD;
    unsigned int* dzb = hdb + NWORD;             // dirty bitmap (k=1 worklist nodes)

    // Build scratch: slab 11.2 + vq 8.39 + iq 3.54 + cnt_v/cidmap/wl_a/b/c 2.0
    // + icnt/islab 0.24 + qc = ~25.4 MB. Preferred home: d_ws (workspace is
    // 256 MiB -- the harness poison fill writes 262144 KB/iter), which makes
    // the fused k_rest_lstm race-free (d_out = pure output). Fallback if ws
    // is small: scratch in d_out + the round-6 separate-dispatch ordering.
    size_t fixed = (size_t)NN * ROW * 4 + (size_t)NN * 4 + 32 * 4 + 3ull * NWORD * 4;
    size_t scratch = (size_t)NN * SLOT * 4 + 8ull * QCAP * 8 + (size_t)IQCAP * 8
                   + 5ull * NN * 4 + (size_t)CIDCAP * 4 + (size_t)CIDCAP * SLOT * 4 + 256;
    bool big_ws = ws_size >= fixed + scratch + 64;
    char* scb = big_ws ? (ws + fixed) : (char*)d_out;
    scb = (char*)(((size_t)scb + 15) & ~(size_t)15);

    int*  slab   = (int*)scb;                    // NN*SLOT ints (valid only)
    int2* vq     = (int2*)(slab + (size_t)NN * SLOT);  // 8 binned valid queues
    int2* iq     = vq + 8 * (size_t)QCAP;        // one global invalid queue
    int*  cnt_v  = (int*)(iq + IQCAP);           // N
    int*  cidmap = cnt_v + NN;                   // N (compact id per cnt_v==0 node)
    int*  wl_a   = cidmap + NN;                  // N (k=1 dirty list, PRESERVED)
    int*  wl_b   = wl_a + NN;                    // N
    int*  wl_c   = wl_b + NN;                    // N (k>=3 ping-pong partner)
    int*  icnt   = wl_c + NN;                    // CIDCAP
    int*  islab  = icnt + CIDCAP;                // CIDCAP*SLOT
    int*  qc     = islab + CIDCAP * SLOT;        // [0..7]=bins, 8=inv, 9=ncid

    k_mt_flags<<<(NN + 63) / 64, 256, 0, stream>>>(x, mask, xx, fill_iter, hzb, hdb, dzb,
                                                   cnt_v, cidmap, icnt, qc, wl_count);
    k_compact<<<(EE + CHUNK - 1) / CHUNK, 256, 0, stream>>>(ei, hzb, hdb, vq, iq, qc);
    k_build<<<2048, 256, 0, stream>>>(vq, qc, cnt_v, slab);
    k_gf_inv<<<GFB + 256, 256, 0, stream>>>(hzb, hdb, cnt_v, slab, fill_iter, xx,
                                            wl_a, wl_count, dzb,
                                            iq, qc, cidmap, icnt, islab, qc + 9);
    if (big_ws) {
        k_rest_lstm<<<1 + (NN + 255) / 256, 256, 0, stream>>>(wl_a, wl_b, wl_c, wl_count,
                                                              cnt_v, cidmap, icnt, islab,
                                                              slab, fill_iter, xx, dzb,
                                                              wih, whh, bih, bhh, out);
    } else {
        k_gather_rest<<<1, 1024, 0, stream>>>(wl_a, wl_b, wl_c, wl_count,
                                              cnt_v, cidmap, icnt, islab,
                                              slab, fill_iter, xx);
        k_lstm_all<<<(NN + 63) / 64, 64, 0, stream>>>(xx, wih, whh, bih, bhh, out);
    }
}

// Round 10
// 222.713 us; speedup vs baseline: 1.0574x; 1.0574x over previous
//
#include <hip/hip_runtime.h>
#include <math.h>

#define TT    32
#define NN    100000
#define FF    2
#define ROW   64        // TT*FF floats per node row
#define EE    1600000
#define MAXIT 20
#define LDSROW 66       // 64 + 2 pad: <=2-way LDS aliasing (free on CDNA4)
#define BIGIT (1 << 29) // fill_iter value for "no data yet" == all-zero row
#define NR    8         // XCD dst-range bins
#define RNG   (NN / NR) // 12500 nodes per bin
#define SLOT  28        // fixed valid slots per node (Poisson(8) in-deg; P(>28)~1e-20)
#define QCAP   131072   // per-bin valid-edge queue capacity (expected ~100K, ~100 sigma)
#define IQCAP  442368   // invalid-edge queue capacity (expected ~400K, ~67 sigma)
#define CIDCAP 2048     // compact ids for nodes with cnt_v==0 (expected ~17)
#define CHUNK  782      // edges per k_compact block (2047 blocks cover EE)
#define NWORD  3126     // ceil(100032/32) bit-array words (12.5 KB -> L1-resident)
#define GFB    1792     // gather blocks in fused gf_inv kernel (+256 inv blocks)

typedef float f32x4 __attribute__((ext_vector_type(4)));
typedef float f32x2 __attribute__((ext_vector_type(2)));

__device__ __forceinline__ float fsig(float x) { return 1.0f / (1.0f + __expf(-x)); }
__device__ __forceinline__ float ftanh(float x) { return 2.0f / (1.0f + __expf(-2.0f * x)) - 1.0f; }

__device__ __forceinline__ bool bit_test(const unsigned int* __restrict__ b, int n) {
    return (b[n >> 5] >> (n & 31)) & 1u;
}

// ---------------------------------------------------------------------------
// Fused: mask + transpose [T,N,F]->[N][64] + fill_iter + hz/hd BIT arrays +
// zero-init of cnt_v/cidmap/icnt/qc/wl_count.
// hz/hd are 12.5KB bit arrays (L1-resident; k_compact/gather probe them 1.6M+
// times). Each block owns exactly 2 bit-words, plain stores, no atomics.
// Staging is the PROVEN round-1 pattern: scalar 4B NT loads + scalar tile
// stores (2-way bank aliasing = free). Round-4's vectorized version ran 3x
// slower (LDS conflicts + branchy bounds) -- do not re-vectorize this staging.
__global__ void k_mt_flags(const float* __restrict__ x, const int* __restrict__ mask,
                           float* __restrict__ xx, int* __restrict__ fill_iter,
                           unsigned int* __restrict__ hzb, unsigned int* __restrict__ hdb,
                           int* __restrict__ cnt_v, int* __restrict__ cidmap,
                           int* __restrict__ icnt, int* __restrict__ qc,
                           int* __restrict__ wl_count) {
    __shared__ float tile[64 * LDSROW];
    __shared__ unsigned int wmH[4], wmD[4];
    const int n0 = blockIdx.x * 64;
    const int tid = threadIdx.x;

    // fused init
    if (tid < 64 && n0 + tid < NN) { cnt_v[n0 + tid] = 0; cidmap[n0 + tid] = 0; }
    if (blockIdx.x == 0) {
        if (tid < 32) wl_count[tid] = 0;
        if (tid >= 32 && tid < 48) qc[tid - 32] = 0;
    }
    if (blockIdx.x < 8) icnt[blockIdx.x * 256 + tid] = 0;

#pragma unroll
    for (int r = 0; r < 16; r++) {
        int flat = r * 256 + tid;          // 0..4095
        int t = flat >> 7;
        int col = flat & 127;
        int gcol = n0 * 2 + col;
        if (gcol < NN * FF) {
            int n = n0 + (col >> 1);
            float v = __builtin_nontemporal_load(x + (size_t)t * (NN * FF) + gcol);
            v = mask[n] ? v : 0.0f;
            tile[(col >> 1) * LDSROW + t * 2 + (col & 1)] = v;
        }
    }
    __syncthreads();

    const int lane = tid & 63, w = tid >> 6;
    unsigned int mwave = 0, dwave = 0;       // hz / hd bits for this wave's 16 nodes
    for (int i = 0; i < 16; i++) {
        int ln = w * 16 + i;
        int n = n0 + ln;
        if (n >= NN) break;                          // wave-uniform
        float v = tile[ln * LDSROW + lane];
        unsigned long long nzm = __ballot(v != 0.0f);
        if (nzm != ~0ull) mwave |= (1u << i);        // row has at least one zero
        if (nzm != 0ull)  dwave |= (1u << i);        // row has at least one datum
        if (lane == 0) fill_iter[n] = (nzm != 0ull) ? 0 : BIGIT;
    }
    if (lane == 0) { wmH[w] = mwave; wmD[w] = dwave; }
    __syncthreads();
    if (tid == 0) {
        hzb[2 * blockIdx.x]     = wmH[0] | (wmH[1] << 16);
        hzb[2 * blockIdx.x + 1] = wmH[2] | (wmH[3] << 16);
        hdb[2 * blockIdx.x]     = wmD[0] | (wmD[1] << 16);
        hdb[2 * blockIdx.x + 1] = wmD[2] | (wmD[3] << 16);
    }

#pragma unroll
    for (int j = 0; j < 4; j++) {
        int flat4 = j * 256 + tid;
        int ln = flat4 >> 4;
        int n = n0 + ln;
        if (n >= NN) continue;
        int off = (flat4 & 15) * 4;
        float4 v;
        v.x = tile[ln * LDSROW + off + 0];
        v.y = tile[ln * LDSROW + off + 1];
        v.z = tile[ln * LDSROW + off + 2];
        v.w = tile[ln * LDSROW + off + 3];
        *(float4*)(xx + (size_t)n * ROW + off) = v;
    }
}

// ---------------------------------------------------------------------------
// Pass A: ONE coalesced NT scan of the edge list. Kept edges (hz dst) binned
// block-locally in LDS into 8 dst-range valid queues + 1 global invalid
// queue; one global atomic per queue per block. src load is UNCONDITIONAL:
// breaks the dst-load -> bit-test -> src-load dependent chain.
__global__ void k_compact(const int* __restrict__ ei, const unsigned int* __restrict__ hzb,
                          const unsigned int* __restrict__ hdb,
                          int2* __restrict__ vq, int2* __restrict__ iq,
                          int* __restrict__ qc) {
    __shared__ int lcnt[9];
    __shared__ int lbase[9];
    const int tid = threadIdx.x;
    if (tid < 9) lcnt[tid] = 0;
    __syncthreads();
    const int e0 = blockIdx.x * CHUNK;
    const int e1 = min(e0 + CHUNK, EE);
    int rs[4], rd[4], rb[4], rp[4];
#pragma unroll
    for (int i = 0; i < 4; i++) {
        rb[i] = -1;
        int e = e0 + i * 256 + tid;
        if (e < e1) {
            int dst = __builtin_nontemporal_load(ei + EE + e);
            int src = __builtin_nontemporal_load(ei + e);   // unconditional
            if (bit_test(hzb, dst)) {
                int b = bit_test(hdb, src) ? (dst / RNG) : 8;
                rs[i] = src; rd[i] = dst; rb[i] = b;
                rp[i] = atomicAdd(&lcnt[b], 1);
            }
        }
    }
    __syncthreads();
    if (tid < 9) lbase[tid] = atomicAdd(&qc[tid], lcnt[tid]);
    __syncthreads();
#pragma unroll
    for (int i = 0; i < 4; i++) {
        if (rb[i] >= 0) {
            int b = rb[i];
            int p = lbase[b] + rp[i];
            if (b < 8) { if (p < QCAP)  vq[b * QCAP + p] = make_int2(rs[i], rd[i]); }
            else       { if (p < IQCAP) iq[p]            = make_int2(rs[i], rd[i]); }
        }
    }
}

// ---------------------------------------------------------------------------
// Pass B: per-XCD bin drains its own queue into its slab slice. Queue (~800KB)
// and slab slice (1.4MB) both stay resident in the bin's L2.
__global__ void k_build(const int2* __restrict__ vq, const int* __restrict__ qc,
                        int* __restrict__ cnt_v, int* __restrict__ slab) {
    const int r = blockIdx.x & 7;
    int n = qc[r]; if (n > QCAP) n = QCAP;
    const int gid = (blockIdx.x >> 3) * blockDim.x + threadIdx.x;
    const int stride = (gridDim.x >> 3) * blockDim.x;
    const int2* q = vq + r * QCAP;
    for (int i = gid; i < n; i += stride) {
        int2 sd = q[i];
        int pos = atomicAdd(&cnt_v[sd.y], 1);
        if (pos < SLOT) slab[sd.y * SLOT + pos] = sd.x;
    }
}

// ---------------------------------------------------------------------------
// Gather body, 4-way neighbor-parallel. Valid extent needs NO per-edge check;
// invalid extent (tiny slab) checks fill_iter<k. zrow=true skips the 256B
// own-row read.
__device__ __forceinline__ void gather_node4(int n, int k, int lane, bool zrow,
                                             int vbeg, int vend, const int* __restrict__ vsl,
                                             int ibeg, int iend, const int* __restrict__ isl,
                                             int* __restrict__ fill_iter,
                                             float* __restrict__ xx,
                                             int* __restrict__ wl_next,
                                             int* __restrict__ wl_count) {
    const int g = lane >> 4;
    const int s = lane & 15;
    float ax = 0.f, ay = 0.f, az = 0.f, aw = 0.f, cntv = 0.f;
#pragma unroll 2
    for (int e = vbeg + g; e < vend; e += 4) {
        int src = vsl[e];                      // broadcast within group
        f32x4 v = ((const f32x4*)(xx + (size_t)src * ROW))[s];
        ax += v.x; ay += v.y; az += v.z; aw += v.w; cntv += 1.f;
    }
    for (int e = ibeg + g; e < iend; e += 4) {
        int src = isl[e];
        if (fill_iter[src] < k) {
            f32x4 v = ((const f32x4*)(xx + (size_t)src * ROW))[s];
            ax += v.x; ay += v.y; az += v.z; aw += v.w; cntv += 1.f;
        }
    }
    // reduce the 4 groups (lane xor 16, 32)
#pragma unroll
    for (int d = 16; d <= 32; d <<= 1) {
        ax += __shfl_xor(ax, d, 64);
        ay += __shfl_xor(ay, d, 64);
        az += __shfl_xor(az, d, 64);
        aw += __shfl_xor(aw, d, 64);
        cntv += __shfl_xor(cntv, d, 64);
    }
    f32x4 own;
    if (zrow) { own.x = 0.f; own.y = 0.f; own.z = 0.f; own.w = 0.f; }
    else        own = ((const f32x4*)(xx + (size_t)n * ROW))[s];
    bool has = cntv > 0.f;
    f32x4 nv;
    nv.x = (own.x == 0.f && has) ? ax / cntv : own.x;
    nv.y = (own.y == 0.f && has) ? ay / cntv : own.y;
    nv.z = (own.z == 0.f && has) ? az / cntv : own.z;
    nv.w = (own.w == 0.f && has) ? aw / cntv : own.w;
    bool allnz = (nv.x != 0.f) & (nv.y != 0.f) & (nv.z != 0.f) & (nv.w != 0.f);
    bool anynz = (nv.x != 0.f) | (nv.y != 0.f) | (nv.z != 0.f) | (nv.w != 0.f);
    unsigned long long ba = __ballot(allnz);
    unsigned long long bn = __ballot(anynz);
    if (g == 0) ((f32x4*)(xx + (size_t)n * ROW))[s] = nv;
    if (lane == 0) {
        if (bn != 0ull && fill_iter[n] > k) fill_iter[n] = k;   // now a valid source
        if (ba != ~0ull) {                     // still has zeros -> next worklist
            int pos = atomicAdd(&wl_count[k], 1);
            wl_next[pos] = n;
        }
    }
}

// ---------------------------------------------------------------------------
// FUSED iteration-1 gather + invalid-queue build (independent work, one
// dispatch): blocks 0..GFB-1 gather over all nodes (L1 hz bit test); blocks
// GFB..GFB+255 filter the invalid queue (final cnt_v==0 dsts ~17 nodes),
// assign compact ids via CAS, fill the tiny inverse slab.
__global__ void k_gf_inv(const unsigned int* __restrict__ hzb,
                         const unsigned int* __restrict__ hdb,
                         const int* __restrict__ cnt_v, const int* __restrict__ slab,
                         int* __restrict__ fill_iter, float* __restrict__ xx,
                         int* __restrict__ wl_next, int* __restrict__ wl_count,
                         const int2* __restrict__ iq, const int* __restrict__ qc,
                         int* __restrict__ cidmap, int* __restrict__ icnt,
                         int* __restrict__ islab, int* __restrict__ ncid) {
    if (blockIdx.x >= GFB) {
        // ---- inv part (256 blocks) ----
        int n = qc[8]; if (n > IQCAP) n = IQCAP;
        const int gid = (blockIdx.x - GFB) * blockDim.x + threadIdx.x;
        const int stride = 256 * blockDim.x;
        for (int i = gid; i < n; i += stride) {
            int2 sd = iq[i];
            if (cnt_v[sd.y] != 0) continue;
            int cid = cidmap[sd.y];
            if (cid == 0) {
                int nid = atomicAdd(ncid, 1) + 1;
                int old = atomicCAS(&cidmap[sd.y], 0, nid);
                cid = old ? old : nid;
            }
            if (cid <= CIDCAP) {
                int pos = atomicAdd(&icnt[cid - 1], 1);
                if (pos < SLOT) islab[(cid - 1) * SLOT + pos] = sd.x;
            }
        }
        return;
    }
    // ---- gather part (GFB blocks) ----
    const int lane = threadIdx.x & 63;
    int wave = (blockIdx.x * blockDim.x + threadIdx.x) >> 6;
    const int nwaves = (GFB * blockDim.x) >> 6;
    for (int n0 = wave; n0 < NN; n0 += nwaves) {
        int n = __builtin_amdgcn_readfirstlane(n0);
        unsigned int hzw = __builtin_amdgcn_readfirstlane(hzb[n >> 5]);
        if (!((hzw >> (n & 31)) & 1u)) continue;     // wave-uniform L1 bit test
        int cv = cnt_v[n]; if (cv > SLOT) cv = SLOT;
        unsigned int hdw = __builtin_amdgcn_readfirstlane(hdb[n >> 5]);
        bool zrow = !((hdw >> (n & 31)) & 1u);
        gather_node4(n, 1, lane, zrow, n * SLOT, n * SLOT + cv, slab, 0, 0, slab,
                     fill_iter, xx, wl_next, wl_count);
    }
}

// ---------------------------------------------------------------------------
// Iterations 2..MAXIT in ONE persistent single-block kernel (worklist after
// iter 1 = nodes with zero valid in-neighbors: ~tens). wl_a preserved; k=2
// reads a->writes b; k>=3 ping-pongs b<->c.
// SEPARATE dispatch from the LSTM: round 9's fused rest+lstm lost ~10us --
// 392x256 grid = 1.53 blocks/CU imbalance AND the shared-kernel regalloc
// gave the LSTM path only 36 VGPRs (loads sunk into the serial recurrence).
__global__ __launch_bounds__(1024)
void k_gather_rest(int* __restrict__ wl_a, int* __restrict__ wl_b,
                   int* __restrict__ wl_c, int* __restrict__ wl_count,
                   const int* __restrict__ cnt_v, const int* __restrict__ cidmap,
                   const int* __restrict__ icnt, const int* __restrict__ islab,
                   const int* __restrict__ slab,
                   int* __restrict__ fill_iter, float* __restrict__ xx) {
    const int lane = threadIdx.x & 63;
    const int wave = threadIdx.x >> 6;       // 0..15
    for (int k = 2; k <= MAXIT; k++) {
        int cnt = atomicAdd(&wl_count[k - 1], 0);   // L2 read, never stale-L1
        if (cnt == 0) break;                        // uniform across block
        int* prev = (k == 2) ? wl_a : ((k & 1) ? wl_b : wl_c);
        int* next = (k & 1) ? wl_c : wl_b;          // k=2->b, k=3->c, k=4->b...
        for (int w = wave; w < cnt; w += 16) {
            int n = __builtin_amdgcn_readfirstlane(prev[w]);
            int cv = cnt_v[n]; if (cv > SLOT) cv = SLOT;
            int cid = cidmap[n];
            int ci = 0, ib = 0;
            if (cid > 0 && cid <= CIDCAP) {
                ci = icnt[cid - 1]; if (ci > SLOT) ci = SLOT;
                ib = (cid - 1) * SLOT;
            }
            bool zrow = (__builtin_amdgcn_readfirstlane(fill_iter[n]) == BIGIT);
            gather_node4(n, k, lane, zrow, n * SLOT, n * SLOT + cv, slab,
                         ib, ib + ci, islab,
                         fill_iter, xx, next, wl_count);
        }
        __threadfence();
        __syncthreads();
    }
}

// ---------------------------------------------------------------------------
// LSTM: one thread per node, hidden=2, gates i,f,g,o. NT loads + NT stores.
// Block=64 -> 1563 blocks (6.1/CU balance; 256-thread grid = 1.5/CU
// imbalance, round-9 lesson). __launch_bounds__(64,1) lets the allocator
// keep the full 64-float row in VGPRs and hoist all 16 loads ahead of the
// serial recurrence (rule #20 + round-9's VGPR=36 load-sinking lesson).
__global__ __launch_bounds__(64, 1)
void k_lstm_all(const float* __restrict__ xx,
                const float* __restrict__ wih, const float* __restrict__ whh,
                const float* __restrict__ bih, const float* __restrict__ bhh,
                float* __restrict__ out) {
    int n = blockIdx.x * 64 + threadIdx.x;
    if (n >= NN) return;
    float Wi[8][2], Wh[8][2], B[8];
#pragma unroll
    for (int kk = 0; kk < 8; kk++) {
        Wi[kk][0] = wih[kk * 2]; Wi[kk][1] = wih[kk * 2 + 1];
        Wh[kk][0] = whh[kk * 2]; Wh[kk][1] = whh[kk * 2 + 1];
        B[kk] = bih[kk] + bhh[kk];
    }
    f32x4 r4[16];
    const f32x4* row4 = (const f32x4*)(xx + (size_t)n * ROW);
#pragma unroll
    for (int i = 0; i < 16; i++) r4[i] = __builtin_nontemporal_load(row4 + i);

    float h0 = 0.f, h1 = 0.f, c0 = 0.f, c1 = 0.f;
#pragma unroll
    for (int t = 0; t < TT; t++) {
        f32x4 q = r4[t >> 1];                 // compile-time index (full unroll)
        float x0 = (t & 1) ? q.z : q.x;
        float x1 = (t & 1) ? q.w : q.y;
        float g[8];
#pragma unroll
        for (int kk = 0; kk < 8; kk++)
            g[kk] = B[kk] + Wi[kk][0] * x0 + Wi[kk][1] * x1 + Wh[kk][0] * h0 + Wh[kk][1] * h1;
        float i0 = fsig(g[0]), i1 = fsig(g[1]);
        float f0 = fsig(g[2]), f1 = fsig(g[3]);
        float gg0 = ftanh(g[4]), gg1 = ftanh(g[5]);
        float o0 = fsig(g[6]), o1 = fsig(g[7]);
        c0 = f0 * c0 + i0 * gg0;
        c1 = f1 * c1 + i1 * gg1;
        h0 = o0 * ftanh(c0);
        h1 = o1 * ftanh(c1);
        f32x2 hv; hv.x = h0; hv.y = h1;
        __builtin_nontemporal_store(hv, (f32x2*)(out + (size_t)t * (NN * FF) + n * 2));
    }
}

// ---------------------------------------------------------------------------
extern "C" void kernel_launch(void* const* d_in, const int* in_sizes, int n_in,
                              void* d_out, int out_size, void* d_ws, size_t ws_size,
                              hipStream_t stream) {
    const float* x    = (const float*)d_in[0];   // [T,N,F]
    const int*   ei   = (const int*)d_in[1];     // [2,E]
    const int*   mask = (const int*)d_in[2];     // [N]
    const float* wih  = (const float*)d_in[6];
    const float* whh  = (const float*)d_in[7];
    const float* bih  = (const float*)d_in[8];
    const float* bhh  = (const float*)d_in[9];
    float* out = (float*)d_out;                  // [T,N,F] fp32

    // Fixed ws region: xx (25.6 MB) + fill_iter + wl_count + hzb/hdb
    char* ws = (char*)d_ws;
    float* xx        = (float*)ws;
    int*   fill_iter = (int*)(ws + (size_t)NN * ROW * 4);
    int*   wl_count  = fill_iter + NN;
    unsigned int* hzb = (unsigned int*)(wl_count + 32);
    unsigned int* hdb = hzb + NWORD;

    // Build scratch (~25.4 MB): preferred home d_ws (256 MiB workspace);
    // fallback d_out (safe: all scratch consumers finish before k_lstm_all).
    size_t fixed = (size_t)NN * ROW * 4 + (size_t)NN * 4 + 32 * 4 + 2ull * NWORD * 4;
    size_t scratch = (size_t)NN * SLOT * 4 + 8ull * QCAP * 8 + (size_t)IQCAP * 8
                   + 5ull * NN * 4 + (size_t)CIDCAP * 4 + (size_t)CIDCAP * SLOT * 4 + 256;
    bool big_ws = ws_size >= fixed + scratch + 64;
    char* scb = big_ws ? (ws + fixed) : (char*)d_out;
    scb = (char*)(((size_t)scb + 15) & ~(size_t)15);

    int*  slab   = (int*)scb;                    // NN*SLOT ints (valid only)
    int2* vq     = (int2*)(slab + (size_t)NN * SLOT);  // 8 binned valid queues
    int2* iq     = vq + 8 * (size_t)QCAP;        // one global invalid queue
    int*  cnt_v  = (int*)(iq + IQCAP);           // N
    int*  cidmap = cnt_v + NN;                   // N (compact id per cnt_v==0 node)
    int*  wl_a   = cidmap + NN;                  // N (k=1 list, PRESERVED)
    int*  wl_b   = wl_a + NN;                    // N
    int*  wl_c   = wl_b + NN;                    // N (k>=3 ping-pong partner)
    int*  icnt   = wl_c + NN;                    // CIDCAP
    int*  islab  = icnt + CIDCAP;                // CIDCAP*SLOT
    int*  qc     = islab + CIDCAP * SLOT;        // [0..7]=bins, 8=inv, 9=ncid

    k_mt_flags<<<(NN + 63) / 64, 256, 0, stream>>>(x, mask, xx, fill_iter, hzb, hdb,
                                                   cnt_v, cidmap, icnt, qc, wl_count);
    k_compact<<<(EE + CHUNK - 1) / CHUNK, 256, 0, stream>>>(ei, hzb, hdb, vq, iq, qc);
    k_build<<<2048, 256, 0, stream>>>(vq, qc, cnt_v, slab);
    k_gf_inv<<<GFB + 256, 256, 0, stream>>>(hzb, hdb, cnt_v, slab, fill_iter, xx,
                                            wl_a, wl_count,
                                            iq, qc, cidmap, icnt, islab, qc + 9);
    k_gather_rest<<<1, 1024, 0, stream>>>(wl_a, wl_b, wl_c, wl_count,
                                          cnt_v, cidmap, icnt, islab,
                                          slab, fill_iter, xx);
    k_lstm_all<<<(NN + 63) / 64, 64, 0, stream>>>(xx, wih, whh, bih, bhh, out);
}